// Round 1
// baseline (1999.902 us; speedup 1.0000x reference)
//
#include <hip/hip_runtime.h>
#include <math.h>

// ---------------------------------------------------------------------------
// SENSE CG reconstruction, B=1, S=4, C=16, H=W=320, rho=0.1, 15 CG iters.
// Strategy: conjugate entire solve by fftshift (even N -> involution), so the
// CG loop uses plain (unshifted) FFTs. ifft2c(fft2c(x)) == x is skipped.
// FFT-320 = Stockham mixed radix 5*4*4*4 in LDS, 64 threads per line.
// ---------------------------------------------------------------------------

#define NDIM 320
#define HHALF 160
#define HW (NDIM*NDIM)
#define NS 4
#define NC 16
#define RHO_ 0.1f
#define CG_ITERS 15

__device__ __forceinline__ float2 cmulf(float2 a, float2 b){
    return make_float2(a.x*b.x - a.y*b.y, a.x*b.y + a.y*b.x);
}

template<int SIGMA>
__device__ __forceinline__ void radix4(const float2* u, float2* v){
    float2 a = make_float2(u[0].x+u[2].x, u[0].y+u[2].y);
    float2 b = make_float2(u[0].x-u[2].x, u[0].y-u[2].y);
    float2 c = make_float2(u[1].x+u[3].x, u[1].y+u[3].y);
    float2 d = make_float2(u[1].x-u[3].x, u[1].y-u[3].y);
    float2 jd = make_float2(-(float)SIGMA*d.y, (float)SIGMA*d.x); // SIGMA*i*d
    v[0] = make_float2(a.x+c.x, a.y+c.y);
    v[1] = make_float2(b.x+jd.x, b.y+jd.y);
    v[2] = make_float2(a.x-c.x, a.y-c.y);
    v[3] = make_float2(b.x-jd.x, b.y-jd.y);
}

template<int SIGMA>
__device__ __forceinline__ void radix5(const float2* u, float2* v){
    const float C1 = 0.30901699437494742f, S1 = 0.95105651629515357f;
    const float C2 = -0.80901699437494745f, S2 = 0.58778525229247312f;
    float2 t1 = make_float2(u[1].x+u[4].x, u[1].y+u[4].y);
    float2 t2 = make_float2(u[2].x+u[3].x, u[2].y+u[3].y);
    float2 t3 = make_float2(u[1].x-u[4].x, u[1].y-u[4].y);
    float2 t4 = make_float2(u[2].x-u[3].x, u[2].y-u[3].y);
    v[0] = make_float2(u[0].x + t1.x + t2.x, u[0].y + t1.y + t2.y);
    float2 m1 = make_float2(u[0].x + C1*t1.x + C2*t2.x, u[0].y + C1*t1.y + C2*t2.y);
    float2 m2 = make_float2(u[0].x + C2*t1.x + C1*t2.x, u[0].y + C2*t1.y + C1*t2.y);
    float2 n1 = make_float2(S1*t3.x + S2*t4.x, S1*t3.y + S2*t4.y);
    float2 n2 = make_float2(S2*t3.x - S1*t4.x, S2*t3.y - S1*t4.y);
    float2 j1 = make_float2(-(float)SIGMA*n1.y, (float)SIGMA*n1.x);
    float2 j2 = make_float2(-(float)SIGMA*n2.y, (float)SIGMA*n2.x);
    v[1] = make_float2(m1.x + j1.x, m1.y + j1.y);
    v[4] = make_float2(m1.x - j1.x, m1.y - j1.y);
    v[2] = make_float2(m2.x + j2.x, m2.y + j2.y);
    v[3] = make_float2(m2.x - j2.x, m2.y - j2.y);
}

// Stockham stage: radix R, cumulative sub-FFT size P. T = N/R butterflies,
// processed by 64 threads (t). Reads in[i+q*T], twiddles by w_{P*R}^{q*(i%P)},
// radix-R DFT, writes out[(i/P)*P*R + i%P + c*P]. Natural order in/out.
template<int R, int P, int SIGMA>
__device__ __forceinline__ void fft_stage(const float2* __restrict__ in,
                                          float2* __restrict__ out, int t)
{
    constexpr int T = NDIM / R;
    for (int i = t; i < T; i += 64) {
        int k  = i % P;
        int jb = i / P;
        float2 u[R];
        #pragma unroll
        for (int q = 0; q < R; ++q) u[q] = in[i + q*T];
        if constexpr (P > 1) {
            float ang = (float)SIGMA * (6.283185307179586f/(float)(P*R)) * (float)k;
            float sn, cs; __sincosf(ang, &sn, &cs);
            float2 w1 = make_float2(cs, sn);
            float2 wc = w1;
            u[1] = cmulf(u[1], wc);
            #pragma unroll
            for (int q = 2; q < R; ++q){ wc = cmulf(wc, w1); u[q] = cmulf(u[q], wc); }
        }
        float2 v[R];
        if constexpr (R == 4) radix4<SIGMA>(u, v); else radix5<SIGMA>(u, v);
        int base = jb*(P*R) + k;
        #pragma unroll
        for (int c = 0; c < R; ++c) out[base + c*P] = v[c];
    }
}

// 320-pt FFT over A (length-320 slice of LDS), B scratch; result back in A.
// SIGMA=-1 forward (numpy fft sign), +1 inverse (unnormalized).
template<int SIGMA>
__device__ __forceinline__ void fft320(float2* A, float2* B, int t)
{
    fft_stage<5,1 ,SIGMA>(A,B,t); __syncthreads();
    fft_stage<4,5 ,SIGMA>(B,A,t); __syncthreads();
    fft_stage<4,20,SIGMA>(A,B,t); __syncthreads();
    fft_stage<4,80,SIGMA>(B,A,t); __syncthreads();
}

__device__ __forceinline__ int sh160(int i){ return i < HHALF ? i + HHALF : i - HHALF; }

// ---------------------------------------------------------------------------
// prep: shifted csm (sP), transposed shifted mask^2/(HW) (mscT[s][w][h]),
//       K = mask'*Sh(kdata)/320 (rhs k-space), zero scalar slots.
__global__ void k_prep(const float2* __restrict__ kin, const float* __restrict__ mask,
                       const float2* __restrict__ csm, float2* __restrict__ sP,
                       float* __restrict__ mscT, float2* __restrict__ K,
                       float* __restrict__ scal)
{
    int gid = blockIdx.x*blockDim.x + threadIdx.x;
    int gsz = gridDim.x*blockDim.x;
    if (gid < 64) scal[gid] = 0.f;
    for (int i = gid; i < NC*HW; i += gsz){
        int w = i % NDIM; int h = (i/NDIM) % NDIM; int c = i/HW;
        sP[i] = csm[(c*NDIM + sh160(h))*NDIM + sh160(w)];
    }
    for (int i = gid; i < NS*HW; i += gsz){
        int h = i % NDIM; int wc = (i/NDIM)%NDIM; int s = i/HW;
        float m = mask[(s*NDIM + sh160(h))*NDIM + sh160(wc)];
        mscT[i] = m*m*(1.0f/102400.0f);  // mask^2 * ortho scale for fwd+inv 2D
    }
    for (int i = gid; i < NS*NC*HW; i += gsz){
        int w = i % NDIM; int h = (i/NDIM)%NDIM; int sc = i/HW;
        int s = sc >> 4;
        int hs = sh160(h), ws = sh160(w);
        float m = mask[(s*NDIM + hs)*NDIM + ws];
        float2 kv = kin[((long)sc*NDIM + hs)*NDIM + ws];
        float f = m*(1.0f/320.0f);       // mask + ortho scale for single inv 2D
        K[i] = make_float2(kv.x*f, kv.y*f);
    }
}

// ---------------------------------------------------------------------------
// PassA: p = r + beta*p (iter>0) fused; K[s,c,h,:] = rowFFT(s'_c .* p).
// grid = S * 80 hgroups * 4 coilgroups; 256 thr = 4 rows x 64.
__global__ __launch_bounds__(256) void k_passA(
    const float2* __restrict__ rv_, const float2* __restrict__ pOld,
    float2* __restrict__ pNew, const float2* __restrict__ sP,
    float2* __restrict__ K, const float* __restrict__ scal, int iter)
{
    int bid = blockIdx.x;
    int cg = bid & 3;
    int hg = (bid>>2) % 80;
    int s  = bid / (4*80);
    int tid = threadIdx.x; int rl = tid>>6; int t = tid&63;
    int h = hg*4 + rl;
    __shared__ float2 bufA[4][NDIM];
    __shared__ float2 bufB[4][NDIM];
    float beta = 0.f;
    if (iter > 0) beta = scal[iter] / (scal[iter-1] + 1e-12f);
    long base = (long)s*HW + h*NDIM;
    float2 pv[5];
    #pragma unroll
    for (int j=0;j<5;++j){
        int idx = t + 64*j;
        float2 rr = rv_[base+idx];
        if (iter > 0){
            float2 pp = pOld[base+idx];
            pv[j] = make_float2(rr.x + beta*pp.x, rr.y + beta*pp.y);
        } else pv[j] = rr;
    }
    if (cg == 0){
        #pragma unroll
        for (int j=0;j<5;++j) pNew[base + t + 64*j] = pv[j];
    }
    for (int c0=0;c0<4;++c0){
        int c = cg*4 + c0;
        const float2* srow = sP + (long)c*HW + h*NDIM;
        #pragma unroll
        for (int j=0;j<5;++j){
            int idx = t+64*j;
            bufA[rl][idx] = cmulf(srow[idx], pv[j]);
        }
        __syncthreads();
        fft320<-1>(&bufA[rl][0], &bufB[rl][0], t);
        long kb = ((long)(s*NC + c))*HW + h*NDIM;
        #pragma unroll
        for (int j=0;j<5;++j){ int idx=t+64*j; K[kb+idx] = bufA[rl][idx]; }
        __syncthreads();
    }
}

// ---------------------------------------------------------------------------
// PassB: per (s,c) image, 8-column LDS tile: colFFT -> mask*scale -> colIFFT
// (doMask=1), or colIFFT only (doMask=0, rhs path). In-place on K.
// grid = S*C*40 tiles; 512 thr = 8 cols x 64.
__global__ __launch_bounds__(512) void k_passB(float2* __restrict__ K,
    const float* __restrict__ mscT, int doMask)
{
    constexpr int L = 324;   // pad: 2-way-max LDS banking on tile load
    int bid = blockIdx.x;
    int wt = bid % 40;
    int sc = bid / 40;
    int s = sc >> 4;
    int tid = threadIdx.x;
    int col = tid >> 6;
    int t = tid & 63;
    int w0 = wt*8;
    __shared__ float2 bufA[8][L];
    __shared__ float2 bufB[8][L];
    long gb = (long)sc*HW;
    int wl = tid & 7, hb = tid >> 3;  // coalesced 64B chunks per 8 lanes
    #pragma unroll
    for (int j=0;j<5;++j){
        int hh = hb + 64*j;
        bufA[wl][hh] = K[gb + (long)hh*NDIM + w0 + wl];
    }
    __syncthreads();
    if (doMask){
        fft320<-1>(&bufA[col][0], &bufB[col][0], t);
        const float* mcol = mscT + (long)s*HW + (long)(w0+col)*NDIM;
        #pragma unroll
        for (int j=0;j<5;++j){
            int hh = t + 64*j;
            float mv = mcol[hh];
            bufA[col][hh].x *= mv; bufA[col][hh].y *= mv;
        }
        __syncthreads();
    }
    fft320<1>(&bufA[col][0], &bufB[col][0], t);
    #pragma unroll
    for (int j=0;j<5;++j){
        int hh = hb + 64*j;
        K[gb + (long)hh*NDIM + w0 + wl] = bufA[wl][hh];
    }
}

// ---------------------------------------------------------------------------
// PassC: rowIFFT of K, conj(s')-combine over 16 coils, +rho*vec, write out,
// fused dot reduction (p.Ap for CG, |r|^2 for rhs). rhs path also zeroes x.
// grid = S*80; 256 thr = 4 rows x 64.
__global__ __launch_bounds__(256) void k_passC(
    const float2* __restrict__ K, const float2* __restrict__ sP,
    const float2* __restrict__ pVec, const float2* __restrict__ Iin,
    float2* __restrict__ outVec, float2* __restrict__ xVec,
    float* __restrict__ scal, int dotSlot, int isRhs)
{
    int bid = blockIdx.x;
    int hg = bid % 80; int s = bid/80;
    int tid = threadIdx.x; int rl = tid>>6; int t = tid&63;
    int h = hg*4 + rl;
    __shared__ float2 bufA[4][NDIM];
    __shared__ float2 bufB[4][NDIM];
    float2 acc[5];
    #pragma unroll
    for (int j=0;j<5;++j) acc[j]=make_float2(0.f,0.f);
    for (int c=0;c<NC;++c){
        long kb = ((long)(s*NC+c))*HW + h*NDIM;
        #pragma unroll
        for (int j=0;j<5;++j){ int idx=t+64*j; bufA[rl][idx]=K[kb+idx]; }
        __syncthreads();
        fft320<1>(&bufA[rl][0], &bufB[rl][0], t);
        const float2* srow = sP + (long)c*HW + h*NDIM;
        #pragma unroll
        for (int j=0;j<5;++j){
            int idx=t+64*j;
            float2 sv = srow[idx]; float2 uv = bufA[rl][idx];
            acc[j].x += sv.x*uv.x + sv.y*uv.y;   // conj(s)*u
            acc[j].y += sv.x*uv.y - sv.y*uv.x;
        }
        __syncthreads();
    }
    long base = (long)s*HW + h*NDIM;
    float dot = 0.f;
    if (isRhs){
        int hs = sh160(h);
        #pragma unroll
        for (int j=0;j<5;++j){
            int idx=t+64*j; int ws = sh160(idx);
            float2 iv = Iin[((long)s*NDIM + hs)*NDIM + ws];
            float2 rr = make_float2(acc[j].x + RHO_*iv.x, acc[j].y + RHO_*iv.y);
            outVec[base+idx] = rr;
            xVec[base+idx] = make_float2(0.f,0.f);
            dot += rr.x*rr.x + rr.y*rr.y;
        }
    } else {
        #pragma unroll
        for (int j=0;j<5;++j){
            int idx=t+64*j;
            float2 pp = pVec[base+idx];
            float2 ap = make_float2(acc[j].x + RHO_*pp.x, acc[j].y + RHO_*pp.y);
            outVec[base+idx] = ap;
            dot += pp.x*ap.x + pp.y*ap.y;
        }
    }
    __syncthreads();
    float* red = (float*)&bufA[0][0];
    red[tid] = dot;
    __syncthreads();
    for (int o=128;o>0;o>>=1){ if (tid<o) red[tid]+=red[tid+o]; __syncthreads(); }
    if (tid==0) atomicAdd(&scal[dotSlot], red[0]);
}

// ---------------------------------------------------------------------------
// x += alpha p ; r -= alpha Ap ; rs_new = |r|^2 -> scal[iter+1]
__global__ __launch_bounds__(256) void k_update(
    float2* __restrict__ x, float2* __restrict__ r,
    const float2* __restrict__ p, const float2* __restrict__ Ap,
    float* __restrict__ scal, int iter)
{
    __shared__ float red[256];
    float alpha = scal[iter] / (scal[16+iter] + 1e-12f);
    int gid = blockIdx.x*blockDim.x + threadIdx.x;
    int gsz = gridDim.x*blockDim.x;
    float rs = 0.f;
    for (int i = gid; i < NS*HW; i += gsz){
        float2 pvv=p[i], av=Ap[i], xv=x[i], rv=r[i];
        xv.x += alpha*pvv.x; xv.y += alpha*pvv.y;
        rv.x -= alpha*av.x;  rv.y -= alpha*av.y;
        x[i]=xv; r[i]=rv;
        rs += rv.x*rv.x + rv.y*rv.y;
    }
    red[threadIdx.x]=rs; __syncthreads();
    for (int o=128;o>0;o>>=1){ if (threadIdx.x<o) red[threadIdx.x]+=red[threadIdx.x+o]; __syncthreads(); }
    if (threadIdx.x==0) atomicAdd(&scal[iter+1], red[0]);
}

// out = Sh(x)  (also equals ifft2c(fft2c(.)) round-trip == identity)
__global__ void k_final(const float2* __restrict__ x, float2* __restrict__ out)
{
    int gid = blockIdx.x*blockDim.x + threadIdx.x;
    int gsz = gridDim.x*blockDim.x;
    for (int i = gid; i < NS*HW; i += gsz){
        int w = i % NDIM; int h = (i/NDIM)%NDIM; int s = i/HW;
        out[i] = x[(long)s*HW + sh160(h)*NDIM + sh160(w)];
    }
}

extern "C" void kernel_launch(void* const* d_in, const int* in_sizes, int n_in,
                              void* d_out, int out_size, void* d_ws, size_t ws_size,
                              hipStream_t stream) {
    (void)in_sizes; (void)n_in; (void)out_size; (void)ws_size;
    const float2* kin  = (const float2*)d_in[0];
    const float2* Iin  = (const float2*)d_in[1];
    const float2* csm  = (const float2*)d_in[2];
    const float*  mask = (const float*)d_in[3];

    char* w = (char*)d_ws;
    size_t off = 0;
    float*  scal = (float*)(w+off);  off += 1024;
    float2* sP   = (float2*)(w+off); off += (size_t)NC*HW*8;
    float*  mscT = (float*)(w+off);  off += (size_t)NS*HW*4;
    float2* K    = (float2*)(w+off); off += (size_t)NS*NC*HW*8;
    float2* x    = (float2*)(w+off); off += (size_t)NS*HW*8;
    float2* r    = (float2*)(w+off); off += (size_t)NS*HW*8;
    float2* pA   = (float2*)(w+off); off += (size_t)NS*HW*8;
    float2* pB   = (float2*)(w+off); off += (size_t)NS*HW*8;
    float2* Ap   = (float2*)(w+off); off += (size_t)NS*HW*8;

    k_prep<<<2048,256,0,stream>>>(kin, mask, csm, sP, mscT, K, scal);
    // rhs: col IFFT then row IFFT + conj(s) combine + rho*img ; writes r, x=0, rs0
    k_passB<<<NS*NC*40,512,0,stream>>>(K, mscT, 0);
    k_passC<<<NS*80,256,0,stream>>>(K, sP, nullptr, Iin, r, x, scal, 0, 1);

    for (int it=0; it<CG_ITERS; ++it){
        float2* pNew = (it&1)? pB : pA;
        float2* pOld = (it&1)? pA : pB;
        k_passA<<<NS*80*4,256,0,stream>>>(r, pOld, pNew, sP, K, scal, it);
        k_passB<<<NS*NC*40,512,0,stream>>>(K, mscT, 1);
        k_passC<<<NS*80,256,0,stream>>>(K, sP, pNew, nullptr, Ap, nullptr, scal, 16+it, 0);
        k_update<<<512,256,0,stream>>>(x, r, pNew, Ap, scal, it);
    }
    k_final<<<512,256,0,stream>>>(x, (float2*)d_out);
}

// Round 2
// 1851.690 us; speedup vs baseline: 1.0800x; 1.0800x over previous
//
#include <hip/hip_runtime.h>
#include <math.h>

// ---------------------------------------------------------------------------
// SENSE CG reconstruction, B=1, S=4, C=16, H=W=320, rho=0.1, 15 CG iters.
// Conjugated by fftshift (even N -> involution): CG loop uses plain FFTs.
// ifft2c(fft2c(x)) == x is skipped. FFT-320 = Stockham 5*4*4*4 in LDS.
// R1: PassC split 4-way by coil-group (320 -> 1280 blocks) with partial
//     coil-combine arrays; Ap assembled in k_update; rho|p|^2 folded into
//     PassA. (R0 passC: 52.9us @ 11.8% occupancy, latency-bound.)
// ---------------------------------------------------------------------------

#define NDIM 320
#define HHALF 160
#define HW (NDIM*NDIM)
#define NS 4
#define NC 16
#define RHO_ 0.1f
#define CG_ITERS 15

__device__ __forceinline__ float2 cmulf(float2 a, float2 b){
    return make_float2(a.x*b.x - a.y*b.y, a.x*b.y + a.y*b.x);
}

template<int SIGMA>
__device__ __forceinline__ void radix4(const float2* u, float2* v){
    float2 a = make_float2(u[0].x+u[2].x, u[0].y+u[2].y);
    float2 b = make_float2(u[0].x-u[2].x, u[0].y-u[2].y);
    float2 c = make_float2(u[1].x+u[3].x, u[1].y+u[3].y);
    float2 d = make_float2(u[1].x-u[3].x, u[1].y-u[3].y);
    float2 jd = make_float2(-(float)SIGMA*d.y, (float)SIGMA*d.x); // SIGMA*i*d
    v[0] = make_float2(a.x+c.x, a.y+c.y);
    v[1] = make_float2(b.x+jd.x, b.y+jd.y);
    v[2] = make_float2(a.x-c.x, a.y-c.y);
    v[3] = make_float2(b.x-jd.x, b.y-jd.y);
}

template<int SIGMA>
__device__ __forceinline__ void radix5(const float2* u, float2* v){
    const float C1 = 0.30901699437494742f, S1 = 0.95105651629515357f;
    const float C2 = -0.80901699437494745f, S2 = 0.58778525229247312f;
    float2 t1 = make_float2(u[1].x+u[4].x, u[1].y+u[4].y);
    float2 t2 = make_float2(u[2].x+u[3].x, u[2].y+u[3].y);
    float2 t3 = make_float2(u[1].x-u[4].x, u[1].y-u[4].y);
    float2 t4 = make_float2(u[2].x-u[3].x, u[2].y-u[3].y);
    v[0] = make_float2(u[0].x + t1.x + t2.x, u[0].y + t1.y + t2.y);
    float2 m1 = make_float2(u[0].x + C1*t1.x + C2*t2.x, u[0].y + C1*t1.y + C2*t2.y);
    float2 m2 = make_float2(u[0].x + C2*t1.x + C1*t2.x, u[0].y + C2*t1.y + C1*t2.y);
    float2 n1 = make_float2(S1*t3.x + S2*t4.x, S1*t3.y + S2*t4.y);
    float2 n2 = make_float2(S2*t3.x - S1*t4.x, S2*t3.y - S1*t4.y);
    float2 j1 = make_float2(-(float)SIGMA*n1.y, (float)SIGMA*n1.x);
    float2 j2 = make_float2(-(float)SIGMA*n2.y, (float)SIGMA*n2.x);
    v[1] = make_float2(m1.x + j1.x, m1.y + j1.y);
    v[4] = make_float2(m1.x - j1.x, m1.y - j1.y);
    v[2] = make_float2(m2.x + j2.x, m2.y + j2.y);
    v[3] = make_float2(m2.x - j2.x, m2.y - j2.y);
}

// Stockham stage: radix R, cumulative sub-FFT size P. Natural order in/out.
template<int R, int P, int SIGMA>
__device__ __forceinline__ void fft_stage(const float2* __restrict__ in,
                                          float2* __restrict__ out, int t)
{
    constexpr int T = NDIM / R;
    for (int i = t; i < T; i += 64) {
        int k  = i % P;
        int jb = i / P;
        float2 u[R];
        #pragma unroll
        for (int q = 0; q < R; ++q) u[q] = in[i + q*T];
        if constexpr (P > 1) {
            float ang = (float)SIGMA * (6.283185307179586f/(float)(P*R)) * (float)k;
            float sn, cs; __sincosf(ang, &sn, &cs);
            float2 w1 = make_float2(cs, sn);
            float2 wc = w1;
            u[1] = cmulf(u[1], wc);
            #pragma unroll
            for (int q = 2; q < R; ++q){ wc = cmulf(wc, w1); u[q] = cmulf(u[q], wc); }
        }
        float2 v[R];
        if constexpr (R == 4) radix4<SIGMA>(u, v); else radix5<SIGMA>(u, v);
        int base = jb*(P*R) + k;
        #pragma unroll
        for (int c = 0; c < R; ++c) out[base + c*P] = v[c];
    }
}

template<int SIGMA>
__device__ __forceinline__ void fft320(float2* A, float2* B, int t)
{
    fft_stage<5,1 ,SIGMA>(A,B,t); __syncthreads();
    fft_stage<4,5 ,SIGMA>(B,A,t); __syncthreads();
    fft_stage<4,20,SIGMA>(A,B,t); __syncthreads();
    fft_stage<4,80,SIGMA>(B,A,t); __syncthreads();
}

__device__ __forceinline__ int sh160(int i){ return i < HHALF ? i + HHALF : i - HHALF; }

// ---------------------------------------------------------------------------
__global__ void k_prep(const float2* __restrict__ kin, const float* __restrict__ mask,
                       const float2* __restrict__ csm, float2* __restrict__ sP,
                       float* __restrict__ mscT, float2* __restrict__ K,
                       float* __restrict__ scal)
{
    int gid = blockIdx.x*blockDim.x + threadIdx.x;
    int gsz = gridDim.x*blockDim.x;
    if (gid < 64) scal[gid] = 0.f;
    for (int i = gid; i < NC*HW; i += gsz){
        int w = i % NDIM; int h = (i/NDIM) % NDIM; int c = i/HW;
        sP[i] = csm[(c*NDIM + sh160(h))*NDIM + sh160(w)];
    }
    for (int i = gid; i < NS*HW; i += gsz){
        int h = i % NDIM; int wc = (i/NDIM)%NDIM; int s = i/HW;
        float m = mask[(s*NDIM + sh160(h))*NDIM + sh160(wc)];
        mscT[i] = m*m*(1.0f/102400.0f);  // mask^2 * ortho scale (fwd+inv 2D)
    }
    for (int i = gid; i < NS*NC*HW; i += gsz){
        int w = i % NDIM; int h = (i/NDIM)%NDIM; int sc = i/HW;
        int s = sc >> 4;
        int hs = sh160(h), ws = sh160(w);
        float m = mask[(s*NDIM + hs)*NDIM + ws];
        float2 kv = kin[((long)sc*NDIM + hs)*NDIM + ws];
        float f = m*(1.0f/320.0f);       // mask + ortho scale for single inv 2D
        K[i] = make_float2(kv.x*f, kv.y*f);
    }
}

// ---------------------------------------------------------------------------
// PassA: p = r + beta*p fused; K[s,c,h,:] = rowFFT(s'_c .* p).
// cg==0 blocks also write pNew and accumulate rho*|p|^2 into scal[16+iter].
// grid = S * 80 hgroups * 4 coilgroups; 256 thr = 4 rows x 64.
__global__ __launch_bounds__(256) void k_passA(
    const float2* __restrict__ rv_, const float2* __restrict__ pOld,
    float2* __restrict__ pNew, const float2* __restrict__ sP,
    float2* __restrict__ K, float* __restrict__ scal, int iter)
{
    int bid = blockIdx.x;
    int cg = bid & 3;
    int hg = (bid>>2) % 80;
    int s  = bid / (4*80);
    int tid = threadIdx.x; int rl = tid>>6; int t = tid&63;
    int h = hg*4 + rl;
    __shared__ float2 bufA[4][NDIM];
    __shared__ float2 bufB[4][NDIM];
    __shared__ float redA[256];
    float beta = 0.f;
    if (iter > 0) beta = scal[iter] / (scal[iter-1] + 1e-12f);
    long base = (long)s*HW + h*NDIM;
    float2 pv[5];
    #pragma unroll
    for (int j=0;j<5;++j){
        int idx = t + 64*j;
        float2 rr = rv_[base+idx];
        if (iter > 0){
            float2 pp = pOld[base+idx];
            pv[j] = make_float2(rr.x + beta*pp.x, rr.y + beta*pp.y);
        } else pv[j] = rr;
    }
    if (cg == 0){   // uniform per block
        float d = 0.f;
        #pragma unroll
        for (int j=0;j<5;++j){
            pNew[base + t + 64*j] = pv[j];
            d += pv[j].x*pv[j].x + pv[j].y*pv[j].y;
        }
        redA[tid] = d; __syncthreads();
        for (int o=128;o>0;o>>=1){ if (tid<o) redA[tid]+=redA[tid+o]; __syncthreads(); }
        if (tid==0) atomicAdd(&scal[16+iter], RHO_*redA[0]);
    }
    for (int c0=0;c0<4;++c0){
        int c = cg*4 + c0;
        const float2* srow = sP + (long)c*HW + h*NDIM;
        #pragma unroll
        for (int j=0;j<5;++j){
            int idx = t+64*j;
            bufA[rl][idx] = cmulf(srow[idx], pv[j]);
        }
        __syncthreads();
        fft320<-1>(&bufA[rl][0], &bufB[rl][0], t);
        long kb = ((long)(s*NC + c))*HW + h*NDIM;
        #pragma unroll
        for (int j=0;j<5;++j){ int idx=t+64*j; K[kb+idx] = bufA[rl][idx]; }
        __syncthreads();
    }
}

// ---------------------------------------------------------------------------
// PassB: per (s,c) image, 8-column LDS tile: colFFT -> mask*scale -> colIFFT
// (doMask=1), or colIFFT only (doMask=0, rhs path). In-place on K.
__global__ __launch_bounds__(512) void k_passB(float2* __restrict__ K,
    const float* __restrict__ mscT, int doMask)
{
    constexpr int L = 324;
    int bid = blockIdx.x;
    int wt = bid % 40;
    int sc = bid / 40;
    int s = sc >> 4;
    int tid = threadIdx.x;
    int col = tid >> 6;
    int t = tid & 63;
    int w0 = wt*8;
    __shared__ float2 bufA[8][L];
    __shared__ float2 bufB[8][L];
    long gb = (long)sc*HW;
    int wl = tid & 7, hb = tid >> 3;  // coalesced 64B chunks per 8 lanes
    #pragma unroll
    for (int j=0;j<5;++j){
        int hh = hb + 64*j;
        bufA[wl][hh] = K[gb + (long)hh*NDIM + w0 + wl];
    }
    __syncthreads();
    if (doMask){
        fft320<-1>(&bufA[col][0], &bufB[col][0], t);
        const float* mcol = mscT + (long)s*HW + (long)(w0+col)*NDIM;
        #pragma unroll
        for (int j=0;j<5;++j){
            int hh = t + 64*j;
            float mv = mcol[hh];
            bufA[col][hh].x *= mv; bufA[col][hh].y *= mv;
        }
        __syncthreads();
    }
    fft320<1>(&bufA[col][0], &bufB[col][0], t);
    #pragma unroll
    for (int j=0;j<5;++j){
        int hh = hb + 64*j;
        K[gb + (long)hh*NDIM + w0 + wl] = bufA[wl][hh];
    }
}

// ---------------------------------------------------------------------------
// PassC2 (CG loop): rowIFFT of 4 coils (one coil-group), conj(s')-combine
// into part[cg], partial p.part dot into scal[dotSlot].
// grid = S*80*4; 256 thr = 4 rows x 64.
__global__ __launch_bounds__(256) void k_passC2(
    const float2* __restrict__ K, const float2* __restrict__ sP,
    const float2* __restrict__ pVec, float2* __restrict__ part,
    float* __restrict__ scal, int dotSlot)
{
    int bid = blockIdx.x;
    int cg = bid & 3;
    int hg = (bid>>2) % 80;
    int s  = bid / (4*80);
    int tid = threadIdx.x; int rl = tid>>6; int t = tid&63;
    int h = hg*4 + rl;
    __shared__ float2 bufA[4][NDIM];
    __shared__ float2 bufB[4][NDIM];
    float2 acc[5];
    #pragma unroll
    for (int j=0;j<5;++j) acc[j]=make_float2(0.f,0.f);
    for (int c0=0;c0<4;++c0){
        int c = cg*4 + c0;
        long kb = ((long)(s*NC+c))*HW + h*NDIM;
        #pragma unroll
        for (int j=0;j<5;++j){ int idx=t+64*j; bufA[rl][idx]=K[kb+idx]; }
        __syncthreads();
        fft320<1>(&bufA[rl][0], &bufB[rl][0], t);
        const float2* srow = sP + (long)c*HW + h*NDIM;
        #pragma unroll
        for (int j=0;j<5;++j){
            int idx=t+64*j;
            float2 sv = srow[idx]; float2 uv = bufA[rl][idx];
            acc[j].x += sv.x*uv.x + sv.y*uv.y;   // conj(s)*u
            acc[j].y += sv.x*uv.y - sv.y*uv.x;
        }
        __syncthreads();
    }
    long pbase = (long)s*HW + h*NDIM;
    long obase = ((long)cg*NS + s)*HW + h*NDIM;
    float dot = 0.f;
    #pragma unroll
    for (int j=0;j<5;++j){
        int idx=t+64*j;
        part[obase+idx] = acc[j];
        float2 pp = pVec[pbase+idx];
        dot += pp.x*acc[j].x + pp.y*acc[j].y;
    }
    __syncthreads();
    float* red = (float*)&bufA[0][0];
    red[tid] = dot;
    __syncthreads();
    for (int o=128;o>0;o>>=1){ if (tid<o) red[tid]+=red[tid+o]; __syncthreads(); }
    if (tid==0) atomicAdd(&scal[dotSlot], red[0]);
}

// ---------------------------------------------------------------------------
// PassC (rhs only, runs once): full 16-coil combine, writes r, x=0, rs0.
__global__ __launch_bounds__(256) void k_passC_rhs(
    const float2* __restrict__ K, const float2* __restrict__ sP,
    const float2* __restrict__ Iin, float2* __restrict__ rOut,
    float2* __restrict__ xVec, float* __restrict__ scal)
{
    int bid = blockIdx.x;
    int hg = bid % 80; int s = bid/80;
    int tid = threadIdx.x; int rl = tid>>6; int t = tid&63;
    int h = hg*4 + rl;
    __shared__ float2 bufA[4][NDIM];
    __shared__ float2 bufB[4][NDIM];
    float2 acc[5];
    #pragma unroll
    for (int j=0;j<5;++j) acc[j]=make_float2(0.f,0.f);
    for (int c=0;c<NC;++c){
        long kb = ((long)(s*NC+c))*HW + h*NDIM;
        #pragma unroll
        for (int j=0;j<5;++j){ int idx=t+64*j; bufA[rl][idx]=K[kb+idx]; }
        __syncthreads();
        fft320<1>(&bufA[rl][0], &bufB[rl][0], t);
        const float2* srow = sP + (long)c*HW + h*NDIM;
        #pragma unroll
        for (int j=0;j<5;++j){
            int idx=t+64*j;
            float2 sv = srow[idx]; float2 uv = bufA[rl][idx];
            acc[j].x += sv.x*uv.x + sv.y*uv.y;
            acc[j].y += sv.x*uv.y - sv.y*uv.x;
        }
        __syncthreads();
    }
    long base = (long)s*HW + h*NDIM;
    float dot = 0.f;
    int hs = sh160(h);
    #pragma unroll
    for (int j=0;j<5;++j){
        int idx=t+64*j; int ws = sh160(idx);
        float2 iv = Iin[((long)s*NDIM + hs)*NDIM + ws];
        float2 rr = make_float2(acc[j].x + RHO_*iv.x, acc[j].y + RHO_*iv.y);
        rOut[base+idx] = rr;
        xVec[base+idx] = make_float2(0.f,0.f);
        dot += rr.x*rr.x + rr.y*rr.y;
    }
    __syncthreads();
    float* red = (float*)&bufA[0][0];
    red[tid] = dot;
    __syncthreads();
    for (int o=128;o>0;o>>=1){ if (tid<o) red[tid]+=red[tid+o]; __syncthreads(); }
    if (tid==0) atomicAdd(&scal[0], red[0]);
}

// ---------------------------------------------------------------------------
// Ap = sum(part) + rho*p assembled on the fly:
// x += alpha p ; r -= alpha Ap ; rs_new = |r|^2 -> scal[iter+1]
__global__ __launch_bounds__(256) void k_update(
    float2* __restrict__ x, float2* __restrict__ r,
    const float2* __restrict__ p, const float2* __restrict__ part,
    float* __restrict__ scal, int iter)
{
    __shared__ float red[256];
    float alpha = scal[iter] / (scal[16+iter] + 1e-12f);
    int gid = blockIdx.x*blockDim.x + threadIdx.x;
    int gsz = gridDim.x*blockDim.x;
    float rs = 0.f;
    const int NV = NS*HW;
    for (int i = gid; i < NV; i += gsz){
        float2 a0=part[i], a1=part[NV+i], a2=part[2*NV+i], a3=part[3*NV+i];
        float2 pvv=p[i], xv=x[i], rv=r[i];
        float2 av = make_float2(a0.x+a1.x+a2.x+a3.x + RHO_*pvv.x,
                                a0.y+a1.y+a2.y+a3.y + RHO_*pvv.y);
        xv.x += alpha*pvv.x; xv.y += alpha*pvv.y;
        rv.x -= alpha*av.x;  rv.y -= alpha*av.y;
        x[i]=xv; r[i]=rv;
        rs += rv.x*rv.x + rv.y*rv.y;
    }
    red[threadIdx.x]=rs; __syncthreads();
    for (int o=128;o>0;o>>=1){ if (threadIdx.x<o) red[threadIdx.x]+=red[threadIdx.x+o]; __syncthreads(); }
    if (threadIdx.x==0) atomicAdd(&scal[iter+1], red[0]);
}

// out = Sh(x)
__global__ void k_final(const float2* __restrict__ x, float2* __restrict__ out)
{
    int gid = blockIdx.x*blockDim.x + threadIdx.x;
    int gsz = gridDim.x*blockDim.x;
    for (int i = gid; i < NS*HW; i += gsz){
        int w = i % NDIM; int h = (i/NDIM)%NDIM; int s = i/HW;
        out[i] = x[(long)s*HW + sh160(h)*NDIM + sh160(w)];
    }
}

extern "C" void kernel_launch(void* const* d_in, const int* in_sizes, int n_in,
                              void* d_out, int out_size, void* d_ws, size_t ws_size,
                              hipStream_t stream) {
    (void)in_sizes; (void)n_in; (void)out_size; (void)ws_size;
    const float2* kin  = (const float2*)d_in[0];
    const float2* Iin  = (const float2*)d_in[1];
    const float2* csm  = (const float2*)d_in[2];
    const float*  mask = (const float*)d_in[3];

    char* w = (char*)d_ws;
    size_t off = 0;
    float*  scal = (float*)(w+off);  off += 1024;
    float2* sP   = (float2*)(w+off); off += (size_t)NC*HW*8;
    float*  mscT = (float*)(w+off);  off += (size_t)NS*HW*4;
    float2* K    = (float2*)(w+off); off += (size_t)NS*NC*HW*8;
    float2* x    = (float2*)(w+off); off += (size_t)NS*HW*8;
    float2* r    = (float2*)(w+off); off += (size_t)NS*HW*8;
    float2* pA   = (float2*)(w+off); off += (size_t)NS*HW*8;
    float2* pB   = (float2*)(w+off); off += (size_t)NS*HW*8;
    float2* part = (float2*)(w+off); off += (size_t)4*NS*HW*8;

    k_prep<<<2048,256,0,stream>>>(kin, mask, csm, sP, mscT, K, scal);
    k_passB<<<NS*NC*40,512,0,stream>>>(K, mscT, 0);
    k_passC_rhs<<<NS*80,256,0,stream>>>(K, sP, Iin, r, x, scal);

    for (int it=0; it<CG_ITERS; ++it){
        float2* pNew = (it&1)? pB : pA;
        float2* pOld = (it&1)? pA : pB;
        k_passA<<<NS*80*4,256,0,stream>>>(r, pOld, pNew, sP, K, scal, it);
        k_passB<<<NS*NC*40,512,0,stream>>>(K, mscT, 1);
        k_passC2<<<NS*80*4,256,0,stream>>>(K, sP, pNew, part, scal, 16+it);
        k_update<<<640,256,0,stream>>>(x, r, pNew, part, scal, it);
    }
    k_final<<<512,256,0,stream>>>(x, (float2*)d_out);
}

// Round 3
// 1808.457 us; speedup vs baseline: 1.1059x; 1.0239x over previous
//
#include <hip/hip_runtime.h>
#include <math.h>

// ---------------------------------------------------------------------------
// SENSE CG reconstruction, B=1, S=4, C=16, H=W=320, rho=0.1, 15 CG iters.
// Conjugated by fftshift (even N): CG loop uses plain FFTs; final
// ifft2c(fft2c(x)) == x skipped. FFT-320 = Stockham 5*4*4*4 in LDS, one
// wave (64 lanes) per line.
// R2: intra-FFT __syncthreads -> zero-cost wave fences (each line is
//     wave-local; DS ops are in-order per wave), software-pipelined coil
//     prefetch, twiddles hoisted to registers (no sincos in loop).
//     R1 evidence: VALUBusy 22%, occ 11% => barrier-drain latency bound.
// ---------------------------------------------------------------------------

#define NDIM 320
#define HHALF 160
#define HW (NDIM*NDIM)
#define NS 4
#define NC 16
#define RHO_ 0.1f
#define CG_ITERS 15

__device__ __forceinline__ void wsync(){
    // wave-local ordering only: no s_barrier, no vmcnt drain.
    __builtin_amdgcn_fence(__ATOMIC_ACQ_REL, "wavefront");
    __builtin_amdgcn_wave_barrier();
}

__device__ __forceinline__ float wred(float v){
    #pragma unroll
    for (int o=32;o>0;o>>=1) v += __shfl_down(v,o,64);
    return v;  // valid on lane 0
}

__device__ __forceinline__ float2 cmulf(float2 a, float2 b){
    return make_float2(a.x*b.x - a.y*b.y, a.x*b.y + a.y*b.x);
}

// multiply by forward twiddle w (SIGMA=-1) or its conjugate (SIGMA=+1)
template<int SIGMA>
__device__ __forceinline__ float2 cmulw(float2 a, float2 w){
    float wy = (SIGMA < 0) ? w.y : -w.y;
    return make_float2(a.x*w.x - a.y*wy, a.x*wy + a.y*w.x);
}

template<int SIGMA>
__device__ __forceinline__ void radix4(const float2* u, float2* v){
    float2 a = make_float2(u[0].x+u[2].x, u[0].y+u[2].y);
    float2 b = make_float2(u[0].x-u[2].x, u[0].y-u[2].y);
    float2 c = make_float2(u[1].x+u[3].x, u[1].y+u[3].y);
    float2 d = make_float2(u[1].x-u[3].x, u[1].y-u[3].y);
    float2 jd = make_float2(-(float)SIGMA*d.y, (float)SIGMA*d.x);
    v[0] = make_float2(a.x+c.x, a.y+c.y);
    v[1] = make_float2(b.x+jd.x, b.y+jd.y);
    v[2] = make_float2(a.x-c.x, a.y-c.y);
    v[3] = make_float2(b.x-jd.x, b.y-jd.y);
}

template<int SIGMA>
__device__ __forceinline__ void radix5(const float2* u, float2* v){
    const float C1 = 0.30901699437494742f, S1 = 0.95105651629515357f;
    const float C2 = -0.80901699437494745f, S2 = 0.58778525229247312f;
    float2 t1 = make_float2(u[1].x+u[4].x, u[1].y+u[4].y);
    float2 t2 = make_float2(u[2].x+u[3].x, u[2].y+u[3].y);
    float2 t3 = make_float2(u[1].x-u[4].x, u[1].y-u[4].y);
    float2 t4 = make_float2(u[2].x-u[3].x, u[2].y-u[3].y);
    v[0] = make_float2(u[0].x + t1.x + t2.x, u[0].y + t1.y + t2.y);
    float2 m1 = make_float2(u[0].x + C1*t1.x + C2*t2.x, u[0].y + C1*t1.y + C2*t2.y);
    float2 m2 = make_float2(u[0].x + C2*t1.x + C1*t2.x, u[0].y + C2*t1.y + C1*t2.y);
    float2 n1 = make_float2(S1*t3.x + S2*t4.x, S1*t3.y + S2*t4.y);
    float2 n2 = make_float2(S2*t3.x - S1*t4.x, S2*t3.y - S1*t4.y);
    float2 j1 = make_float2(-(float)SIGMA*n1.y, (float)SIGMA*n1.x);
    float2 j2 = make_float2(-(float)SIGMA*n2.y, (float)SIGMA*n2.x);
    v[1] = make_float2(m1.x + j1.x, m1.y + j1.y);
    v[4] = make_float2(m1.x - j1.x, m1.y - j1.y);
    v[2] = make_float2(m2.x + j2.x, m2.y + j2.y);
    v[3] = make_float2(m2.x - j2.x, m2.y - j2.y);
}

// Per-thread hoisted forward twiddles (exp(-2*pi*i*k/PR)); thread t always
// owns butterflies i=t and (t<16) i=t+64 in each radix-4 stage.
struct Tw { float2 w20a, w20b, w80a, w80b, w320a, w320b; };

__device__ __forceinline__ Tw make_tw(int t){
    Tw tw; float sn, cs;
    const float n2pi = -6.283185307179586f;
    __sincosf(n2pi*(float)(t%5)    /20.f,  &sn,&cs); tw.w20a = make_float2(cs,sn);
    __sincosf(n2pi*(float)((t+4)%5)/20.f,  &sn,&cs); tw.w20b = make_float2(cs,sn);
    __sincosf(n2pi*(float)(t%20)    /80.f, &sn,&cs); tw.w80a = make_float2(cs,sn);
    __sincosf(n2pi*(float)((t+4)%20)/80.f, &sn,&cs); tw.w80b = make_float2(cs,sn);
    __sincosf(n2pi*(float)t      /320.f,   &sn,&cs); tw.w320a= make_float2(cs,sn);
    __sincosf(n2pi*(float)(t+64) /320.f,   &sn,&cs); tw.w320b= make_float2(cs,sn);
    return tw;
}

template<int SIGMA>
__device__ __forceinline__ void bfly5(const float2* __restrict__ in,
                                      float2* __restrict__ out, int i){
    float2 u[5];
    #pragma unroll
    for (int q=0;q<5;++q) u[q] = in[i + q*64];
    float2 v[5];
    radix5<SIGMA>(u,v);
    #pragma unroll
    for (int c=0;c<5;++c) out[i*5 + c] = v[c];
}

template<int SIGMA, int P>
__device__ __forceinline__ void bfly4(const float2* __restrict__ in,
                                      float2* __restrict__ out, int i, float2 w1){
    const int T = 80;
    int k = i % P, jb = i / P;
    float2 u[4];
    #pragma unroll
    for (int q=0;q<4;++q) u[q] = in[i + q*T];
    float2 w2 = cmulf(w1,w1);
    float2 w3 = cmulf(w2,w1);
    u[1] = cmulw<SIGMA>(u[1], w1);
    u[2] = cmulw<SIGMA>(u[2], w2);
    u[3] = cmulw<SIGMA>(u[3], w3);
    float2 v[4];
    radix4<SIGMA>(u,v);
    int base = jb*(4*P) + k;
    #pragma unroll
    for (int c=0;c<4;++c) out[base + c*P] = v[c];
}

// 320-pt FFT over A (wave-local line), B scratch; result back in A.
template<int SIGMA>
__device__ __forceinline__ void fft320w(float2* __restrict__ A,
                                        float2* __restrict__ B,
                                        int t, const Tw& tw){
    wsync();
    bfly5<SIGMA>(A,B,t);
    wsync();
    bfly4<SIGMA,5>(B,A,t, tw.w20a);
    if (t<16) bfly4<SIGMA,5>(B,A,t+64, tw.w20b);
    wsync();
    bfly4<SIGMA,20>(A,B,t, tw.w80a);
    if (t<16) bfly4<SIGMA,20>(A,B,t+64, tw.w80b);
    wsync();
    bfly4<SIGMA,80>(B,A,t, tw.w320a);
    if (t<16) bfly4<SIGMA,80>(B,A,t+64, tw.w320b);
    wsync();
}

__device__ __forceinline__ int sh160(int i){ return i < HHALF ? i + HHALF : i - HHALF; }

// ---------------------------------------------------------------------------
__global__ void k_prep(const float2* __restrict__ kin, const float* __restrict__ mask,
                       const float2* __restrict__ csm, float2* __restrict__ sP,
                       float* __restrict__ mscT, float2* __restrict__ K,
                       float* __restrict__ scal)
{
    int gid = blockIdx.x*blockDim.x + threadIdx.x;
    int gsz = gridDim.x*blockDim.x;
    if (gid < 64) scal[gid] = 0.f;
    for (int i = gid; i < NC*HW; i += gsz){
        int w = i % NDIM; int h = (i/NDIM) % NDIM; int c = i/HW;
        sP[i] = csm[(c*NDIM + sh160(h))*NDIM + sh160(w)];
    }
    for (int i = gid; i < NS*HW; i += gsz){
        int h = i % NDIM; int wc = (i/NDIM)%NDIM; int s = i/HW;
        float m = mask[(s*NDIM + sh160(h))*NDIM + sh160(wc)];
        mscT[i] = m*m*(1.0f/102400.0f);  // mask^2 * ortho scale (fwd+inv 2D)
    }
    for (int i = gid; i < NS*NC*HW; i += gsz){
        int w = i % NDIM; int h = (i/NDIM)%NDIM; int sc = i/HW;
        int s = sc >> 4;
        int hs = sh160(h), ws = sh160(w);
        float m = mask[(s*NDIM + hs)*NDIM + ws];
        float2 kv = kin[((long)sc*NDIM + hs)*NDIM + ws];
        float f = m*(1.0f/320.0f);
        K[i] = make_float2(kv.x*f, kv.y*f);
    }
}

// ---------------------------------------------------------------------------
// PassA: p = r + beta*p fused; K[s,c,h,:] = rowFFT(s'_c .* p).
// cg==0 blocks also write pNew and add rho*|p|^2 to scal[16+iter].
// grid = S*80*4 ; 256 thr = 4 waves, one row per wave.
__global__ __launch_bounds__(256) void k_passA(
    const float2* __restrict__ rv_, const float2* __restrict__ pOld,
    float2* __restrict__ pNew, const float2* __restrict__ sP,
    float2* __restrict__ K, float* __restrict__ scal, int iter)
{
    int bid = blockIdx.x;
    int cg = bid & 3;
    int hg = (bid>>2) % 80;
    int s  = bid / (4*80);
    int tid = threadIdx.x; int rl = tid>>6; int t = tid&63;
    int h = hg*4 + rl;
    __shared__ float2 bufA[4][NDIM];
    __shared__ float2 bufB[4][NDIM];
    float2* A = &bufA[rl][0];
    float2* B = &bufB[rl][0];
    Tw tw = make_tw(t);
    float beta = 0.f;
    if (iter > 0) beta = scal[iter] / (scal[iter-1] + 1e-12f);
    long base = (long)s*HW + h*NDIM;
    float2 pv[5];
    #pragma unroll
    for (int j=0;j<5;++j){
        int idx = t + 64*j;
        float2 rr = rv_[base+idx];
        if (iter > 0){
            float2 pp = pOld[base+idx];
            pv[j] = make_float2(rr.x + beta*pp.x, rr.y + beta*pp.y);
        } else pv[j] = rr;
    }
    if (cg == 0){
        float d = 0.f;
        #pragma unroll
        for (int j=0;j<5;++j){
            pNew[base + t + 64*j] = pv[j];
            d += pv[j].x*pv[j].x + pv[j].y*pv[j].y;
        }
        float wd = wred(d);
        if (t==0) atomicAdd(&scal[16+iter], RHO_*wd);
    }
    int c = cg*4;
    const float2* srow = sP + (long)c*HW + h*NDIM;
    float2 sv[5];
    #pragma unroll
    for (int j=0;j<5;++j) sv[j] = srow[t+64*j];
    #pragma unroll
    for (int c0=0;c0<4;++c0){
        #pragma unroll
        for (int j=0;j<5;++j) A[t+64*j] = cmulf(sv[j], pv[j]);
        float2 sv2[5];
        if (c0<3){
            const float2* sr2 = srow + (long)(c0+1)*HW;
            #pragma unroll
            for (int j=0;j<5;++j) sv2[j] = sr2[t+64*j];
        }
        fft320w<-1>(A,B,t,tw);
        long kb = ((long)(s*NC + c + c0))*HW + h*NDIM;
        #pragma unroll
        for (int j=0;j<5;++j){ int idx=t+64*j; K[kb+idx] = A[idx]; }
        wsync();
        if (c0<3){
            #pragma unroll
            for (int j=0;j<5;++j) sv[j]=sv2[j];
        }
    }
}

// ---------------------------------------------------------------------------
// PassB: per (s,c) image, 8-column LDS tile: colFFT -> mask*scale -> colIFFT
// (doMask=1) or colIFFT only (doMask=0). In-place on K.
// 512 thr = 8 waves, one column per wave; 2 block barriers total.
__global__ __launch_bounds__(512) void k_passB(float2* __restrict__ K,
    const float* __restrict__ mscT, int doMask)
{
    constexpr int L = 324;
    int bid = blockIdx.x;
    int wt = bid % 40;
    int sc = bid / 40;
    int s = sc >> 4;
    int tid = threadIdx.x;
    int col = tid >> 6;
    int t = tid & 63;
    int w0 = wt*8;
    __shared__ float2 bufA[8][L];
    __shared__ float2 bufB[8][L];
    Tw tw = make_tw(t);
    float mv[5];
    if (doMask){
        const float* mcol = mscT + (long)s*HW + (long)(w0+col)*NDIM;
        #pragma unroll
        for (int j=0;j<5;++j) mv[j] = mcol[t+64*j];
    }
    long gb = (long)sc*HW;
    int wl = tid & 7, hb = tid >> 3;  // coalesced 64B chunks
    #pragma unroll
    for (int j=0;j<5;++j){
        int hh = hb + 64*j;
        bufA[wl][hh] = K[gb + (long)hh*NDIM + w0 + wl];
    }
    __syncthreads();
    float2* A = &bufA[col][0];
    float2* B = &bufB[col][0];
    if (doMask){
        fft320w<-1>(A,B,t,tw);
        #pragma unroll
        for (int j=0;j<5;++j){
            int hh = t + 64*j;
            A[hh].x *= mv[j]; A[hh].y *= mv[j];
        }
        fft320w<1>(A,B,t,tw);
    } else {
        fft320w<1>(A,B,t,tw);
    }
    __syncthreads();
    #pragma unroll
    for (int j=0;j<5;++j){
        int hh = hb + 64*j;
        K[gb + (long)hh*NDIM + w0 + wl] = bufA[wl][hh];
    }
}

// ---------------------------------------------------------------------------
// PassC2: rowIFFT of one coil-group (4 coils), conj(s')-combine into
// part[cg]; optional partial p.part dot into scal[dotSlot].
// grid = S*80*4 ; 256 thr = 4 waves, one row per wave. Prefetched coil loop.
__global__ __launch_bounds__(256) void k_passC2(
    const float2* __restrict__ K, const float2* __restrict__ sP,
    const float2* __restrict__ pVec, float2* __restrict__ part,
    float* __restrict__ scal, int dotSlot, int doDot)
{
    int bid = blockIdx.x;
    int cg = bid & 3;
    int hg = (bid>>2) % 80;
    int s  = bid / (4*80);
    int tid = threadIdx.x; int rl = tid>>6; int t = tid&63;
    int h = hg*4 + rl;
    __shared__ float2 bufA[4][NDIM];
    __shared__ float2 bufB[4][NDIM];
    __shared__ float redS[4];
    float2* A = &bufA[rl][0];
    float2* B = &bufB[rl][0];
    Tw tw = make_tw(t);
    int c = cg*4;
    long kb0 = ((long)(s*NC + c))*HW + h*NDIM;
    const float2* srow = sP + (long)c*HW + h*NDIM;
    float2 kv[5], sv[5];
    #pragma unroll
    for (int j=0;j<5;++j){ int idx=t+64*j; kv[j]=K[kb0+idx]; sv[j]=srow[idx]; }
    float2 acc[5];
    #pragma unroll
    for (int j=0;j<5;++j) acc[j]=make_float2(0.f,0.f);
    #pragma unroll
    for (int c0=0;c0<4;++c0){
        #pragma unroll
        for (int j=0;j<5;++j) A[t+64*j] = kv[j];
        float2 kv2[5], sv2[5];
        if (c0<3){
            long kb = kb0 + (long)(c0+1)*HW;
            const float2* sr2 = srow + (long)(c0+1)*HW;
            #pragma unroll
            for (int j=0;j<5;++j){ int idx=t+64*j; kv2[j]=K[kb+idx]; sv2[j]=sr2[idx]; }
        }
        fft320w<1>(A,B,t,tw);
        #pragma unroll
        for (int j=0;j<5;++j){
            float2 uv = A[t+64*j];
            acc[j].x += sv[j].x*uv.x + sv[j].y*uv.y;   // conj(s)*u
            acc[j].y += sv[j].x*uv.y - sv[j].y*uv.x;
        }
        wsync();
        if (c0<3){
            #pragma unroll
            for (int j=0;j<5;++j){ kv[j]=kv2[j]; sv[j]=sv2[j]; }
        }
    }
    long pbase = (long)s*HW + h*NDIM;
    long obase = ((long)cg*NS + s)*HW + h*NDIM;
    float dot = 0.f;
    #pragma unroll
    for (int j=0;j<5;++j){
        int idx=t+64*j;
        part[obase+idx] = acc[j];
        if (doDot){
            float2 pp = pVec[pbase+idx];
            dot += pp.x*acc[j].x + pp.y*acc[j].y;
        }
    }
    if (doDot){
        float wd = wred(dot);
        if (t==0) redS[rl] = wd;
        __syncthreads();
        if (tid==0) atomicAdd(&scal[dotSlot], redS[0]+redS[1]+redS[2]+redS[3]);
    }
}

// ---------------------------------------------------------------------------
// rhs assembly: r = sum(part) + rho*Sh(I) ; x = 0 ; rs0 -> scal[0]
__global__ __launch_bounds__(256) void k_rhs_fin(
    const float2* __restrict__ part, const float2* __restrict__ Iin,
    float2* __restrict__ r, float2* __restrict__ x, float* __restrict__ scal)
{
    __shared__ float red[256];
    int gid = blockIdx.x*blockDim.x + threadIdx.x;
    int gsz = gridDim.x*blockDim.x;
    float rs = 0.f;
    const int NV = NS*HW;
    for (int i = gid; i < NV; i += gsz){
        int w = i % NDIM; int h = (i/NDIM)%NDIM; int s = i/HW;
        float2 iv = Iin[((long)s*NDIM + sh160(h))*NDIM + sh160(w)];
        float2 a0=part[i], a1=part[NV+i], a2=part[2*NV+i], a3=part[3*NV+i];
        float2 rr = make_float2(a0.x+a1.x+a2.x+a3.x + RHO_*iv.x,
                                a0.y+a1.y+a2.y+a3.y + RHO_*iv.y);
        r[i] = rr;
        x[i] = make_float2(0.f,0.f);
        rs += rr.x*rr.x + rr.y*rr.y;
    }
    red[threadIdx.x]=rs; __syncthreads();
    for (int o=128;o>0;o>>=1){ if (threadIdx.x<o) red[threadIdx.x]+=red[threadIdx.x+o]; __syncthreads(); }
    if (threadIdx.x==0) atomicAdd(&scal[0], red[0]);
}

// ---------------------------------------------------------------------------
// Ap = sum(part) + rho*p on the fly:
// x += alpha p ; r -= alpha Ap ; rs_new -> scal[iter+1]
__global__ __launch_bounds__(256) void k_update(
    float2* __restrict__ x, float2* __restrict__ r,
    const float2* __restrict__ p, const float2* __restrict__ part,
    float* __restrict__ scal, int iter)
{
    __shared__ float red[256];
    float alpha = scal[iter] / (scal[16+iter] + 1e-12f);
    int gid = blockIdx.x*blockDim.x + threadIdx.x;
    int gsz = gridDim.x*blockDim.x;
    float rs = 0.f;
    const int NV = NS*HW;
    for (int i = gid; i < NV; i += gsz){
        float2 a0=part[i], a1=part[NV+i], a2=part[2*NV+i], a3=part[3*NV+i];
        float2 pvv=p[i], xv=x[i], rv=r[i];
        float2 av = make_float2(a0.x+a1.x+a2.x+a3.x + RHO_*pvv.x,
                                a0.y+a1.y+a2.y+a3.y + RHO_*pvv.y);
        xv.x += alpha*pvv.x; xv.y += alpha*pvv.y;
        rv.x -= alpha*av.x;  rv.y -= alpha*av.y;
        x[i]=xv; r[i]=rv;
        rs += rv.x*rv.x + rv.y*rv.y;
    }
    red[threadIdx.x]=rs; __syncthreads();
    for (int o=128;o>0;o>>=1){ if (threadIdx.x<o) red[threadIdx.x]+=red[threadIdx.x+o]; __syncthreads(); }
    if (threadIdx.x==0) atomicAdd(&scal[iter+1], red[0]);
}

// out = Sh(x)
__global__ void k_final(const float2* __restrict__ x, float2* __restrict__ out)
{
    int gid = blockIdx.x*blockDim.x + threadIdx.x;
    int gsz = gridDim.x*blockDim.x;
    for (int i = gid; i < NS*HW; i += gsz){
        int w = i % NDIM; int h = (i/NDIM)%NDIM; int s = i/HW;
        out[i] = x[(long)s*HW + sh160(h)*NDIM + sh160(w)];
    }
}

extern "C" void kernel_launch(void* const* d_in, const int* in_sizes, int n_in,
                              void* d_out, int out_size, void* d_ws, size_t ws_size,
                              hipStream_t stream) {
    (void)in_sizes; (void)n_in; (void)out_size; (void)ws_size;
    const float2* kin  = (const float2*)d_in[0];
    const float2* Iin  = (const float2*)d_in[1];
    const float2* csm  = (const float2*)d_in[2];
    const float*  mask = (const float*)d_in[3];

    char* w = (char*)d_ws;
    size_t off = 0;
    float*  scal = (float*)(w+off);  off += 1024;
    float2* sP   = (float2*)(w+off); off += (size_t)NC*HW*8;
    float*  mscT = (float*)(w+off);  off += (size_t)NS*HW*4;
    float2* K    = (float2*)(w+off); off += (size_t)NS*NC*HW*8;
    float2* x    = (float2*)(w+off); off += (size_t)NS*HW*8;
    float2* r    = (float2*)(w+off); off += (size_t)NS*HW*8;
    float2* pA   = (float2*)(w+off); off += (size_t)NS*HW*8;
    float2* pB   = (float2*)(w+off); off += (size_t)NS*HW*8;
    float2* part = (float2*)(w+off); off += (size_t)4*NS*HW*8;

    k_prep<<<2048,256,0,stream>>>(kin, mask, csm, sP, mscT, K, scal);
    k_passB<<<NS*NC*40,512,0,stream>>>(K, mscT, 0);
    k_passC2<<<NS*80*4,256,0,stream>>>(K, sP, r, part, scal, 63, 0);
    k_rhs_fin<<<640,256,0,stream>>>(part, Iin, r, x, scal);

    for (int it=0; it<CG_ITERS; ++it){
        float2* pNew = (it&1)? pB : pA;
        float2* pOld = (it&1)? pA : pB;
        k_passA<<<NS*80*4,256,0,stream>>>(r, pOld, pNew, sP, K, scal, it);
        k_passB<<<NS*NC*40,512,0,stream>>>(K, mscT, 1);
        k_passC2<<<NS*80*4,256,0,stream>>>(K, sP, pNew, part, scal, 16+it, 1);
        k_update<<<640,256,0,stream>>>(x, r, pNew, part, scal, it);
    }
    k_final<<<512,256,0,stream>>>(x, (float2*)d_out);
}